// Round 1
// baseline (253.294 us; speedup 1.0000x reference)
//
#include <hip/hip_runtime.h>

// FGPillarMaxPooling on MI355X (gfx950)
// Config constants from the reference:
//   PCR = (-51.2, -51.2, -5.0, 51.2, 51.2, 3.0), PS = 0.2
//   GW = GH = 512, B = 4, N = 800000, CIN = 4, COUT = 32
// Output: (B*GH*GW, COUT) fp32 = 33,554,432 floats = 128 MiB.
//
// Strategy:
//  - h = relu(gf @ W) >= 0 and empty segments map to 0, so zero-init output
//    and use unsigned-int atomicMax on the float bit pattern (monotone for
//    non-negative floats).
//  - One 32-lane group per point, lane index == output channel. Each lane:
//    7 FMAs against LDS-cached W, one atomic. 32 lanes per point target a
//    contiguous 128B span -> good atomic locality, 1 VMEM atomic instr /
//    2 points / wave.

#define GW 512
#define GH 512
#define COUT 32
#define PTS_PER_BLOCK 8   // 256 threads / 32 channels

__global__ __launch_bounds__(256) void pillar_fwd(
    const float* __restrict__ xyz,        // (N,3)
    const int*   __restrict__ cnt,        // (B,)
    const float4* __restrict__ feat,      // (N,4) as float4
    const float* __restrict__ W,          // (7,32) row-major
    unsigned int* __restrict__ out,       // (B*GH*GW, 32) float bits
    int N, int B)
{
    __shared__ float sW[7 * COUT];
    int tid = threadIdx.x;
    if (tid < 7 * COUT) sW[tid] = W[tid];
    __syncthreads();

    int p = blockIdx.x * PTS_PER_BLOCK + (tid >> 5);
    int c = tid & 31;
    if (p >= N) return;

    float x = xyz[3 * p + 0];
    float y = xyz[3 * p + 1];
    float z = xyz[3 * p + 2];

    // batch index from prefix sums of cnt (B is small; uniform loads broadcast)
    int b = 0, acc = 0;
    for (int k = 0; k < B; ++k) {
        acc += cnt[k];
        b += (p >= acc) ? 1 : 0;
    }

    // pillar cell — keep IEEE division to match the reference's floor decisions
    int px = (int)floorf((x - (-51.2f)) / 0.2f);
    int py = (int)floorf((y - (-51.2f)) / 0.2f);
    px = min(max(px, 0), GW - 1);
    py = min(max(py, 0), GH - 1);

    float cx = ((float)px + 0.5f) * 0.2f + (-51.2f);
    float cy = ((float)py + 0.5f) * 0.2f + (-51.2f);
    // cz = 0.5*(-5.0 + 3.0) = -1.0  ->  z - cz = z + 1.0
    float g4 = x - cx;
    float g5 = y - cy;
    float g6 = z + 1.0f;

    float4 f = feat[p];

    float h = f.x * sW[0 * COUT + c]
            + f.y * sW[1 * COUT + c]
            + f.z * sW[2 * COUT + c]
            + f.w * sW[3 * COUT + c]
            + g4  * sW[4 * COUT + c]
            + g5  * sW[5 * COUT + c]
            + g6  * sW[6 * COUT + c];
    h = fmaxf(h, 0.0f);

    unsigned int seg = (unsigned int)b * (GH * GW) + (unsigned int)py * GW + (unsigned int)px;
    atomicMax(out + (size_t)seg * COUT + c, __float_as_uint(h));
}

extern "C" void kernel_launch(void* const* d_in, const int* in_sizes, int n_in,
                              void* d_out, int out_size, void* d_ws, size_t ws_size,
                              hipStream_t stream) {
    const float*  xyz  = (const float*)d_in[0];
    const int*    cnt  = (const int*)d_in[1];
    const float4* feat = (const float4*)d_in[2];
    const float*  W    = (const float*)d_in[3];
    unsigned int* out  = (unsigned int*)d_out;

    int N = in_sizes[0] / 3;
    int B = in_sizes[1];

    // Output is re-poisoned to 0xAA before every timed launch — zero it.
    hipMemsetAsync(d_out, 0, (size_t)out_size * sizeof(float), stream);

    int grid = (N + PTS_PER_BLOCK - 1) / PTS_PER_BLOCK;
    pillar_fwd<<<grid, 256, 0, stream>>>(xyz, cnt, feat, W, out, N, B);
}